// Round 1
// baseline (8428.267 us; speedup 1.0000x reference)
//
#include <hip/hip_runtime.h>

#define T_STEPS 2048
#define NBATCH  256
#define EDIM    128
#define HDIM    256
#define NVOCAB  50001
#define NGROUPS 16     // batch groups of 16 rows
#define NSLICES 32     // j-slices of 8 per group (x4 gates = 32 cols per WG)
#define NBLOCKS (NGROUPS*NSLICES)

typedef _Float16 half8 __attribute__((ext_vector_type(8)));
typedef float    floatx4 __attribute__((ext_vector_type(4)));
typedef unsigned int uint32;

// ws layout (flags/hbuf first so small-ws still works; emb16 only if ws is big)
#define FLAGS_OFF   0                       // [2][16][32] int   = 4 KB
#define HBUF_OFF    4096                    // [2][16][16][256] f16 = 256 KB
#define EMB16_OFF   (4096 + 262144)
#define EMB16_BYTES (NVOCAB*EDIM*2)         // 12.8 MB
#define WS_NEED_BIG (EMB16_OFF + EMB16_BYTES)

__device__ __forceinline__ float sigm(float x){ return 1.0f/(1.0f + __expf(-x)); }
__device__ __forceinline__ float tanh_fast(float x){ return 2.0f/(1.0f + __expf(-2.0f*x)) - 1.0f; }

__global__ void emb_cvt_kernel(const float* __restrict__ src, _Float16* __restrict__ dst, int n4){
    int stride = gridDim.x * blockDim.x;
    for (int i = blockIdx.x*blockDim.x + threadIdx.x; i < n4; i += stride) {
        const float4 v = ((const float4*)src)[i];
        union { _Float16 h[4]; uint2 u; } p;
        p.h[0] = (_Float16)v.x; p.h[1] = (_Float16)v.y;
        p.h[2] = (_Float16)v.z; p.h[3] = (_Float16)v.w;
        ((uint2*)dst)[i] = p.u;
    }
}

__global__ __launch_bounds__(64, 2) void lstm_persist(
    const int*   __restrict__ tok,
    const float* __restrict__ emb32,
    const float* __restrict__ Wih,
    const float* __restrict__ Whh,
    const float* __restrict__ bih,
    const float* __restrict__ bhh,
    const float* __restrict__ Wout,
    const float* __restrict__ bout,
    float*       __restrict__ out,
    char*        __restrict__ ws,
    const _Float16* __restrict__ emb16,
    int use16)
{
    const int L      = threadIdx.x;      // 0..63
    const int lane15 = L & 15;
    const int quad   = L >> 4;           // 0..3
    const int bid    = blockIdx.x;       // 0..511
    // XCD-locality heuristic: all 32 slices of a group share bid%8 (same XCD
    // under round-robin dispatch). Correctness does not depend on it.
    const int grp    = (bid & 7)*2 + (bid >> 8);   // 0..15
    const int slc    = (bid >> 3) & 31;            // 0..31

    int*      flags = (int*)(ws + FLAGS_OFF);       // [2][16][32]
    _Float16* hbuf  = (_Float16*)(ws + HBUF_OFF);   // [2][16][16][256]

    // ---- persistent weight fragments (register-resident across all 2048 steps) ----
    // B-operand layout (16x16x32): col n = lane&15, k = (lane>>4)*8 + i
    half8 bfr[2][12];
    float bias[2];
    #pragma unroll
    for (int tile = 0; tile < 2; ++tile) {
        const int nloc = tile*16 + lane15;          // 0..31 : gate-major, 8 j per gate
        const int gate = nloc >> 3;
        const int jj   = nloc & 7;
        const int ng   = gate*HDIM + slc*8 + jj;    // global 4H column (row of W)
        bias[tile] = bih[ng] + bhh[ng];
        #pragma unroll
        for (int kt = 0; kt < 12; ++kt) {
            const int k0 = kt*32 + quad*8;
            const float* p = (kt < 4) ? (Wih + ng*EDIM + k0)
                                      : (Whh + ng*HDIM + (k0 - EDIM));
            half8 h;
            #pragma unroll
            for (int i = 0; i < 8; ++i) h[i] = (_Float16)p[i];
            bfr[tile][kt] = h;
        }
    }

    // ---- token / x prefetch pipeline (2 deep) ----
    const int btok = grp*16 + lane15;               // batch row for lane's A-row
    auto ldx = [&](int tk, int kt) -> half8 {
        const int k0 = kt*32 + quad*8;
        if (use16) {
            return *(const half8*)(emb16 + (long)tk*EDIM + k0);
        } else {
            const float* p = emb32 + (long)tk*EDIM + k0;
            half8 h;
            #pragma unroll
            for (int i = 0; i < 8; ++i) h[i] = (_Float16)p[i];
            return h;
        }
    };

    int tok_next = tok[NBATCH + btok];              // token for step 1
    half8 xcur[4], xnext[4];
    {
        int tok0 = tok[btok];
        #pragma unroll
        for (int kt = 0; kt < 4; ++kt) xcur[kt] = ldx(tok0, kt);
    }

    float c[4] = {0.f, 0.f, 0.f, 0.f};
    const bool act = (lane15 < 8);
    const bool stl = act && !(lane15 & 1);
    const int  jj8 = lane15 & 7;

    #pragma unroll 1
    for (int t = 0; t < T_STEPS; ++t) {
        // prefetch x(t+1) and token(t+2)
        if (t + 1 < T_STEPS) {
            #pragma unroll
            for (int kt = 0; kt < 4; ++kt) xnext[kt] = ldx(tok_next, kt);
        }
        int tok_nn = 0;
        if (t + 2 < T_STEPS) tok_nn = tok[(t+2)*NBATCH + btok];

        floatx4 acc0 = {0.f,0.f,0.f,0.f};
        floatx4 acc1 = {0.f,0.f,0.f,0.f};

        // x-part MFMAs first (overlap with flag spin below)
        #pragma unroll
        for (int kt = 0; kt < 4; ++kt) {
            acc0 = __builtin_amdgcn_mfma_f32_16x16x32_f16(xcur[kt], bfr[0][kt], acc0, 0,0,0);
            acc1 = __builtin_amdgcn_mfma_f32_16x16x32_f16(xcur[kt], bfr[1][kt], acc1, 0,0,0);
        }

        if (t > 0) {
            const int parR = (t-1) & 1;
            int* fl = flags + parR*(NGROUPS*NSLICES) + grp*NSLICES + (L & 31);
            int cnt = 0;
            while (true) {
                int v = __hip_atomic_load(fl, __ATOMIC_RELAXED, __HIP_MEMORY_SCOPE_AGENT);
                if (__all(v >= t)) break;
                if (++cnt > (1<<15)) break;    // safety: no hang on bug
                __builtin_amdgcn_s_sleep(1);
            }
            asm volatile("" ::: "memory");
            // A-operand from broadcast h: row m = lane&15, k = (lane>>4)*8 (+32 per kt)
            const _Float16* hr = hbuf + (parR*NGROUPS + grp)*(16*HDIM) + lane15*HDIM;
            #pragma unroll
            for (int kt = 4; kt < 12; ++kt) {
                const int j0 = (kt-4)*32 + quad*8;
                const uint32* hp = (const uint32*)(hr + j0);
                union { uint32 u[4]; half8 h; } hf;
                hf.u[0] = __hip_atomic_load(hp+0, __ATOMIC_RELAXED, __HIP_MEMORY_SCOPE_AGENT);
                hf.u[1] = __hip_atomic_load(hp+1, __ATOMIC_RELAXED, __HIP_MEMORY_SCOPE_AGENT);
                hf.u[2] = __hip_atomic_load(hp+2, __ATOMIC_RELAXED, __HIP_MEMORY_SCOPE_AGENT);
                hf.u[3] = __hip_atomic_load(hp+3, __ATOMIC_RELAXED, __HIP_MEMORY_SCOPE_AGENT);
                acc0 = __builtin_amdgcn_mfma_f32_16x16x32_f16(hf.h, bfr[0][kt], acc0, 0,0,0);
                acc1 = __builtin_amdgcn_mfma_f32_16x16x32_f16(hf.h, bfr[1][kt], acc1, 0,0,0);
            }
        }

        // gates: C/D layout col=lane&15, row=quad*4+reg.
        // tile0 cols: i (jj<8) | f (jj>=8); tile1 cols: g | o  -> xor8 pairs them.
        uint32 hdw[4];
        #pragma unroll
        for (int r = 0; r < 4; ++r) {
            float p0 = acc0[r] + bias[0];
            float p1 = acc1[r] + bias[1];
            float fpre = __int_as_float(__builtin_amdgcn_ds_swizzle(__float_as_int(p0), 0x201F)); // lane^8
            float opre = __int_as_float(__builtin_amdgcn_ds_swizzle(__float_as_int(p1), 0x201F));
            float iv = sigm(p0);
            float fv = sigm(fpre);
            float gv = tanh_fast(p1);
            float ov = sigm(opre);
            float cn = fv * c[r] + iv * gv;
            c[r] = cn;
            float hv = ov * tanh_fast(cn);
            union { _Float16 f; unsigned short u; } cvh; cvh.f = (_Float16)hv;
            uint32 hu = cvh.u;
            uint32 part = (uint32)__builtin_amdgcn_ds_swizzle((int)hu, 0x041F);  // lane^1
            hdw[r] = (hu & 0xFFFFu) | (part << 16);
        }
        // broadcast h slice (even-jj lanes store f16 pairs), then release flag
        {
            _Float16* hwb = hbuf + (((t&1)*NGROUPS) + grp)*(16*HDIM);
            if (stl) {
                #pragma unroll
                for (int r = 0; r < 4; ++r) {
                    const int m = quad*4 + r;
                    uint32* dst = (uint32*)(hwb + m*HDIM + slc*8 + jj8);
                    __hip_atomic_store(dst, hdw[r], __ATOMIC_RELAXED, __HIP_MEMORY_SCOPE_AGENT);
                }
            }
            asm volatile("s_waitcnt vmcnt(0)" ::: "memory");
            if (L == 0) {
                int* myf = flags + (t&1)*(NGROUPS*NSLICES) + grp*NSLICES + slc;
                __hip_atomic_store(myf, t+1, __ATOMIC_RELAXED, __HIP_MEMORY_SCOPE_AGENT);
            }
        }
        // rotate prefetch pipeline
        #pragma unroll
        for (int kt = 0; kt < 4; ++kt) xcur[kt] = xnext[kt];
        tok_next = tok_nn;
    }

    // ---- output: slice-0 WG of each group does y = sigmoid(h_T . W_out + b) ----
    if (slc == 0) {
        const int parF = (T_STEPS-1) & 1;
        int* fl = flags + parF*(NGROUPS*NSLICES) + grp*NSLICES + (L & 31);
        int cnt = 0;
        while (true) {
            int v = __hip_atomic_load(fl, __ATOMIC_RELAXED, __HIP_MEMORY_SCOPE_AGENT);
            if (__all(v >= T_STEPS)) break;
            if (++cnt > (1<<15)) break;
            __builtin_amdgcn_s_sleep(1);
        }
        asm volatile("" ::: "memory");
        const int m  = L >> 2;       // 0..15
        const int pp = L & 3;        // quarter of H
        const _Float16* hr = hbuf + (parF*NGROUPS + grp)*(16*HDIM) + m*HDIM;
        const uint32* hp = (const uint32*)hr + pp*32;
        float sum = 0.f;
        #pragma unroll
        for (int d = 0; d < 32; ++d) {
            uint32 u = __hip_atomic_load(hp + d, __ATOMIC_RELAXED, __HIP_MEMORY_SCOPE_AGENT);
            union { uint32 u; _Float16 h[2]; } cv; cv.u = u;
            const int j = pp*64 + d*2;
            sum += (float)cv.h[0] * Wout[j] + (float)cv.h[1] * Wout[j+1];
        }
        sum += __int_as_float(__builtin_amdgcn_ds_swizzle(__float_as_int(sum), 0x041F));
        sum += __int_as_float(__builtin_amdgcn_ds_swizzle(__float_as_int(sum), 0x081F));
        if (pp == 0) out[grp*16 + m] = sigm(sum + bout[0]);
    }
}

extern "C" void kernel_launch(void* const* d_in, const int* in_sizes, int n_in,
                              void* d_out, int out_size, void* d_ws, size_t ws_size,
                              hipStream_t stream) {
    const int*   tokp = (const int*)  d_in[0];
    const float* emb  = (const float*)d_in[1];
    const float* Wih  = (const float*)d_in[2];
    const float* Whh  = (const float*)d_in[3];
    const float* bih  = (const float*)d_in[4];
    const float* bhh  = (const float*)d_in[5];
    const float* Wout = (const float*)d_in[6];
    const float* bout = (const float*)d_in[7];
    float* out = (float*)d_out;
    char*  ws  = (char*)d_ws;

    const int use16 = (ws_size >= (size_t)WS_NEED_BIG) ? 1 : 0;
    _Float16* emb16 = (_Float16*)(ws + EMB16_OFF);
    if (use16) {
        emb_cvt_kernel<<<1024, 256, 0, stream>>>(emb, emb16, NVOCAB*EDIM/4);
    }
    lstm_persist<<<NBLOCKS, 64, 0, stream>>>(tokp, emb, Wih, Whh, bih, bhh, Wout, bout,
                                             out, ws, emb16, use16);
}

// Round 2
// 5478.542 us; speedup vs baseline: 1.5384x; 1.5384x over previous
//
#include <hip/hip_runtime.h>

#define T_STEPS 2048
#define NBATCH  256
#define EDIM    128
#define HDIM    256
#define NVOCAB  50001
#define NGROUPS 16
#define NSLICES 32
#define NBLOCKS (NGROUPS*NSLICES)

typedef _Float16 half8 __attribute__((ext_vector_type(8)));
typedef float    floatx4 __attribute__((ext_vector_type(4)));
typedef unsigned int uint32;

// ---------------- shared math ----------------
#define LOG2E 1.4426950408889634f
__device__ __forceinline__ float sigm2(float x){
    return __builtin_amdgcn_rcpf(1.0f + __builtin_amdgcn_exp2f(-x * LOG2E));
}
__device__ __forceinline__ float tanh2(float x){
    return 1.0f - 2.0f * __builtin_amdgcn_rcpf(1.0f + __builtin_amdgcn_exp2f(x * (2.0f*LOG2E)));
}
__device__ __forceinline__ float sigm(float x){ return 1.0f/(1.0f + __expf(-x)); }
__device__ __forceinline__ float tanh_fast(float x){ return 2.0f/(1.0f + __expf(-2.0f*x)) - 1.0f; }

// ============================================================================
// PATH B (ws >= 102.4 MB): xg vocab table + single-CU persistent groups
// ============================================================================
#define TABLE_BYTES ((size_t)NVOCAB * 1024 * 2)   // 102,402,048

// xg_table: xgp[v][w][l15][n] (f16, 8 n's contiguous = 16B) =
//   sum_e W_ih[col(n,w,l15), e] * emb[v, e] + b_ih[col] + b_hh[col]
// col(n,w,l15) = (n>>1)*256 + w*32 + (n&1)*16 + l15
// Writer: 1 wave per (64-v tile, w). M=64 via 4 mfma tiles; D layout col=lane&15,
// row=quad*4+r makes the permuted store a coalesced dwordx4 per (mt,r).
__global__ __launch_bounds__(64, 1) void xg_table(
    const float* __restrict__ emb,
    const float* __restrict__ Wih,
    const float* __restrict__ bih,
    const float* __restrict__ bhh,
    _Float16*    __restrict__ xgp)
{
    const int L  = threadIdx.x;
    const int l15 = L & 15;
    const int q   = L >> 4;
    const int w   = blockIdx.x & 7;
    const int v0  = (blockIdx.x >> 3) * 64;

    half8 bfr[8][4];
    float bias[8];
    #pragma unroll
    for (int n = 0; n < 8; ++n) {
        const int col = (n >> 1)*256 + w*32 + (n & 1)*16 + l15;
        bias[n] = bih[col] + bhh[col];
        #pragma unroll
        for (int kt = 0; kt < 4; ++kt) {
            const float* p = Wih + col*EDIM + kt*32 + q*8;
            const float4 f0 = *(const float4*)p;
            const float4 f1 = *(const float4*)(p + 4);
            half8 h;
            h[0]=(_Float16)f0.x; h[1]=(_Float16)f0.y; h[2]=(_Float16)f0.z; h[3]=(_Float16)f0.w;
            h[4]=(_Float16)f1.x; h[5]=(_Float16)f1.y; h[6]=(_Float16)f1.z; h[7]=(_Float16)f1.w;
            bfr[n][kt] = h;
        }
    }

    floatx4 acc[4][8];
    #pragma unroll
    for (int mt = 0; mt < 4; ++mt)
        #pragma unroll
        for (int n = 0; n < 8; ++n) acc[mt][n] = (floatx4){0.f,0.f,0.f,0.f};

    #pragma unroll
    for (int mt = 0; mt < 4; ++mt) {
        int v = v0 + mt*16 + l15;
        if (v > NVOCAB-1) v = NVOCAB-1;
        #pragma unroll
        for (int kt = 0; kt < 4; ++kt) {
            const float* p = emb + (size_t)v*EDIM + kt*32 + q*8;
            const float4 f0 = *(const float4*)p;
            const float4 f1 = *(const float4*)(p + 4);
            half8 a;
            a[0]=(_Float16)f0.x; a[1]=(_Float16)f0.y; a[2]=(_Float16)f0.z; a[3]=(_Float16)f0.w;
            a[4]=(_Float16)f1.x; a[5]=(_Float16)f1.y; a[6]=(_Float16)f1.z; a[7]=(_Float16)f1.w;
            #pragma unroll
            for (int n = 0; n < 8; ++n)
                acc[mt][n] = __builtin_amdgcn_mfma_f32_16x16x32_f16(a, bfr[n][kt], acc[mt][n], 0,0,0);
        }
    }

    #pragma unroll
    for (int mt = 0; mt < 4; ++mt) {
        #pragma unroll
        for (int r = 0; r < 4; ++r) {
            const int v = v0 + mt*16 + q*4 + r;
            if (v <= NVOCAB-1) {
                union { int4 i4; _Float16 h[8]; } pk;
                #pragma unroll
                for (int n = 0; n < 8; ++n) pk.h[n] = (_Float16)(acc[mt][n][r] + bias[n]);
                *(int4*)(xgp + (size_t)v*1024 + w*128 + l15*8) = pk.i4;
            }
        }
    }
}

// Persistent LSTM: 16 blocks x 512 threads (8 waves). Wave w owns gate cols
// {gate*256 + w*32 + u*16 + l15}. W_hh fp8-e4m3 register-resident (128 VGPRs).
// h broadcast through LDS (fp8), one __syncthreads per step. No global sync.
#define H8_STRIDE 264
#define H8_BUF    (16*H8_STRIDE)            // 4224 B per parity
#define SM_H8     0
#define SM_HF16   (2*H8_BUF)                // 8448
#define SM_RED    (SM_HF16 + 16*256*2)      // 16640
#define SM_TOTAL  (SM_RED + 256*4)          // 17664

__global__ __launch_bounds__(512, 2) void lstm_table(
    const int*   __restrict__ tok,
    const float* __restrict__ Whh,
    const float* __restrict__ Wout,
    const float* __restrict__ bout,
    const _Float16* __restrict__ xgp,
    float*       __restrict__ out)
{
    __shared__ char smem[SM_TOTAL];
    const int tid = threadIdx.x;
    const int w   = tid >> 6;
    const int L   = tid & 63;
    const int l15 = L & 15;
    const int q   = L >> 4;
    const int g16 = blockIdx.x * 16;

    // ---- W_hh -> fp8 register fragments: bfr[n][kt], k = kt*32 + q*8 + byte ----
    long bfr[8][8];
    #pragma unroll
    for (int n = 0; n < 8; ++n) {
        const int col = (n >> 1)*256 + w*32 + (n & 1)*16 + l15;
        #pragma unroll
        for (int kt = 0; kt < 8; ++kt) {
            const float* p = Whh + col*HDIM + kt*32 + q*8;
            const float4 f0 = *(const float4*)p;
            const float4 f1 = *(const float4*)(p + 4);
            int lo = __builtin_amdgcn_cvt_pk_fp8_f32(f0.x, f0.y, 0, false);
            lo     = __builtin_amdgcn_cvt_pk_fp8_f32(f0.z, f0.w, lo, true);
            int hi = __builtin_amdgcn_cvt_pk_fp8_f32(f1.x, f1.y, 0, false);
            hi     = __builtin_amdgcn_cvt_pk_fp8_f32(f1.z, f1.w, hi, true);
            bfr[n][kt] = (long)(((unsigned long)(unsigned)hi << 32) | (unsigned)lo);
        }
    }

    // ---- pipeline init: xg(t=0) and tokens(t=1) ----
    union Hx { int4 v; _Float16 h[8]; };
    int4 xg_cur[4], xg_nxt[4];
    int4 tkc, tkn;
    {
        int4 tk0 = *(const int4*)(tok + g16 + q*4);
        const int* t0 = (const int*)&tk0;
        #pragma unroll
        for (int r = 0; r < 4; ++r)
            xg_cur[r] = *(const int4*)(xgp + (size_t)t0[r]*1024 + w*128 + l15*8);
        tkc = *(const int4*)(tok + NBATCH + g16 + q*4);
    }

    float c[8];
    #pragma unroll
    for (int i = 0; i < 8; ++i) c[i] = 0.f;

    #pragma unroll 1
    for (int t = 0; t < T_STEPS; ++t) {
        // prefetch tokens(t+2) and xg(t+1)
        if (t + 2 < T_STEPS) tkn = *(const int4*)(tok + (t+2)*NBATCH + g16 + q*4);
        if (t + 1 < T_STEPS) {
            const int* tc = (const int*)&tkc;
            #pragma unroll
            for (int r = 0; r < 4; ++r)
                xg_nxt[r] = *(const int4*)(xgp + (size_t)tc[r]*1024 + w*128 + l15*8);
        }

        // acc init from xg fragments (C/D layout: col=l15, row=q*4+r)
        floatx4 acc[8];
        #pragma unroll
        for (int r = 0; r < 4; ++r) {
            Hx hx; hx.v = xg_cur[r];
            #pragma unroll
            for (int n = 0; n < 8; ++n) acc[n][r] = (float)hx.h[n];
        }

        // recurrent GEMM from LDS h (fp8): A[m=l15][k=kt*32+q*8+byte]
        if (t > 0) {
            const char* hrow = smem + SM_H8 + ((t-1) & 1)*H8_BUF + l15*H8_STRIDE + q*8;
            #pragma unroll
            for (int kt = 0; kt < 8; ++kt) {
                const long af = *(const long*)(hrow + kt*32);
                #pragma unroll
                for (int n = 0; n < 8; ++n)
                    acc[n] = __builtin_amdgcn_mfma_f32_16x16x32_fp8_fp8(af, bfr[n][kt], acc[n], 0,0,0);
            }
        }

        // gates: lane holds i,f,g,o for (row=q*4+r, j=w*32+u*16+l15) at n={u,2+u,4+u,6+u}
        char* h8w  = smem + SM_H8 + (t & 1)*H8_BUF;
        const bool last = (t == T_STEPS-1);
        #pragma unroll
        for (int u = 0; u < 2; ++u) {
            #pragma unroll
            for (int r = 0; r < 4; ++r) {
                const float iv = sigm2(acc[0+u][r]);
                const float fv = sigm2(acc[2+u][r]);
                const float gv = tanh2(acc[4+u][r]);
                const float ov = sigm2(acc[6+u][r]);
                const int ci = u*4 + r;
                const float cn = fv * c[ci] + iv * gv;
                c[ci] = cn;
                const float hv = ov * tanh2(cn);
                const int row = q*4 + r;
                const int j   = w*32 + u*16 + l15;
                if (last) {
                    *(_Float16*)(smem + SM_HF16 + (row*256 + j)*2) = (_Float16)hv;
                } else {
                    const int pk = __builtin_amdgcn_cvt_pk_fp8_f32(hv, hv, 0, false);
                    *(char*)(h8w + row*H8_STRIDE + j) = (char)pk;
                }
            }
        }
        __syncthreads();

        #pragma unroll
        for (int r = 0; r < 4; ++r) xg_cur[r] = xg_nxt[r];
        tkc = tkn;
    }

    // ---- output: y = sigmoid(h_T . W_out + b) ----
    float* red = (float*)(smem + SM_RED);
    if (tid < 256) {
        const int b = tid >> 4, seg = tid & 15;
        const _Float16* hr = (const _Float16*)(smem + SM_HF16) + b*256 + seg*16;
        const float* wo = Wout + seg*16;
        float s = 0.f;
        #pragma unroll
        for (int jj = 0; jj < 16; ++jj) s += (float)hr[jj] * wo[jj];
        red[tid] = s;
    }
    __syncthreads();
    if (tid < 16) {
        float s = 0.f;
        #pragma unroll
        for (int k = 0; k < 16; ++k) s += red[tid*16 + k];
        out[g16 + tid] = sigm2(s + bout[0]);
    }
}

// ============================================================================
// PATH A (fallback, ws < 102.4 MB): Round-1 kernel (proven, ~8.4 ms)
// ============================================================================
#define FLAGS_OFF   0
#define HBUF_OFF    4096
#define EMB16_OFF   (4096 + 262144)
#define EMB16_BYTES (NVOCAB*EDIM*2)
#define WS_NEED_BIG (EMB16_OFF + EMB16_BYTES)

__global__ void emb_cvt_kernel(const float* __restrict__ src, _Float16* __restrict__ dst, int n4){
    int stride = gridDim.x * blockDim.x;
    for (int i = blockIdx.x*blockDim.x + threadIdx.x; i < n4; i += stride) {
        const float4 v = ((const float4*)src)[i];
        union { _Float16 h[4]; uint2 u; } p;
        p.h[0] = (_Float16)v.x; p.h[1] = (_Float16)v.y;
        p.h[2] = (_Float16)v.z; p.h[3] = (_Float16)v.w;
        ((uint2*)dst)[i] = p.u;
    }
}

__global__ __launch_bounds__(64, 2) void lstm_persist(
    const int*   __restrict__ tok,
    const float* __restrict__ emb32,
    const float* __restrict__ Wih,
    const float* __restrict__ Whh,
    const float* __restrict__ bih,
    const float* __restrict__ bhh,
    const float* __restrict__ Wout,
    const float* __restrict__ bout,
    float*       __restrict__ out,
    char*        __restrict__ ws,
    const _Float16* __restrict__ emb16,
    int use16)
{
    const int L      = threadIdx.x;
    const int lane15 = L & 15;
    const int quad   = L >> 4;
    const int bid    = blockIdx.x;
    const int grp    = (bid & 7)*2 + (bid >> 8);
    const int slc    = (bid >> 3) & 31;

    int*      flags = (int*)(ws + FLAGS_OFF);
    _Float16* hbuf  = (_Float16*)(ws + HBUF_OFF);

    half8 bfr[2][12];
    float bias[2];
    #pragma unroll
    for (int tile = 0; tile < 2; ++tile) {
        const int nloc = tile*16 + lane15;
        const int gate = nloc >> 3;
        const int jj   = nloc & 7;
        const int ng   = gate*HDIM + slc*8 + jj;
        bias[tile] = bih[ng] + bhh[ng];
        #pragma unroll
        for (int kt = 0; kt < 12; ++kt) {
            const int k0 = kt*32 + quad*8;
            const float* p = (kt < 4) ? (Wih + ng*EDIM + k0)
                                      : (Whh + ng*HDIM + (k0 - EDIM));
            half8 h;
            #pragma unroll
            for (int i = 0; i < 8; ++i) h[i] = (_Float16)p[i];
            bfr[tile][kt] = h;
        }
    }

    const int btok = grp*16 + lane15;
    auto ldx = [&](int tk, int kt) -> half8 {
        const int k0 = kt*32 + quad*8;
        if (use16) {
            return *(const half8*)(emb16 + (long)tk*EDIM + k0);
        } else {
            const float* p = emb32 + (long)tk*EDIM + k0;
            half8 h;
            #pragma unroll
            for (int i = 0; i < 8; ++i) h[i] = (_Float16)p[i];
            return h;
        }
    };

    int tok_next = tok[NBATCH + btok];
    half8 xcur[4], xnext[4];
    {
        int tok0 = tok[btok];
        #pragma unroll
        for (int kt = 0; kt < 4; ++kt) xcur[kt] = ldx(tok0, kt);
    }

    float c[4] = {0.f, 0.f, 0.f, 0.f};
    const bool act = (lane15 < 8);
    const bool stl = act && !(lane15 & 1);
    const int  jj8 = lane15 & 7;

    #pragma unroll 1
    for (int t = 0; t < T_STEPS; ++t) {
        if (t + 1 < T_STEPS) {
            #pragma unroll
            for (int kt = 0; kt < 4; ++kt) xnext[kt] = ldx(tok_next, kt);
        }
        int tok_nn = 0;
        if (t + 2 < T_STEPS) tok_nn = tok[(t+2)*NBATCH + btok];

        floatx4 acc0 = {0.f,0.f,0.f,0.f};
        floatx4 acc1 = {0.f,0.f,0.f,0.f};

        #pragma unroll
        for (int kt = 0; kt < 4; ++kt) {
            acc0 = __builtin_amdgcn_mfma_f32_16x16x32_f16(xcur[kt], bfr[0][kt], acc0, 0,0,0);
            acc1 = __builtin_amdgcn_mfma_f32_16x16x32_f16(xcur[kt], bfr[1][kt], acc1, 0,0,0);
        }

        if (t > 0) {
            const int parR = (t-1) & 1;
            int* fl = flags + parR*(NGROUPS*NSLICES) + grp*NSLICES + (L & 31);
            int cnt = 0;
            while (true) {
                int v = __hip_atomic_load(fl, __ATOMIC_RELAXED, __HIP_MEMORY_SCOPE_AGENT);
                if (__all(v >= t)) break;
                if (++cnt > (1<<15)) break;
                __builtin_amdgcn_s_sleep(1);
            }
            asm volatile("" ::: "memory");
            const _Float16* hr = hbuf + (parR*NGROUPS + grp)*(16*HDIM) + lane15*HDIM;
            #pragma unroll
            for (int kt = 4; kt < 12; ++kt) {
                const int j0 = (kt-4)*32 + quad*8;
                const uint32* hp = (const uint32*)(hr + j0);
                union { uint32 u[4]; half8 h; } hf;
                hf.u[0] = __hip_atomic_load(hp+0, __ATOMIC_RELAXED, __HIP_MEMORY_SCOPE_AGENT);
                hf.u[1] = __hip_atomic_load(hp+1, __ATOMIC_RELAXED, __HIP_MEMORY_SCOPE_AGENT);
                hf.u[2] = __hip_atomic_load(hp+2, __ATOMIC_RELAXED, __HIP_MEMORY_SCOPE_AGENT);
                hf.u[3] = __hip_atomic_load(hp+3, __ATOMIC_RELAXED, __HIP_MEMORY_SCOPE_AGENT);
                acc0 = __builtin_amdgcn_mfma_f32_16x16x32_f16(hf.h, bfr[0][kt], acc0, 0,0,0);
                acc1 = __builtin_amdgcn_mfma_f32_16x16x32_f16(hf.h, bfr[1][kt], acc1, 0,0,0);
            }
        }

        uint32 hdw[4];
        #pragma unroll
        for (int r = 0; r < 4; ++r) {
            float p0 = acc0[r] + bias[0];
            float p1 = acc1[r] + bias[1];
            float fpre = __int_as_float(__builtin_amdgcn_ds_swizzle(__float_as_int(p0), 0x201F));
            float opre = __int_as_float(__builtin_amdgcn_ds_swizzle(__float_as_int(p1), 0x201F));
            float iv = sigm(p0);
            float fv = sigm(fpre);
            float gv = tanh_fast(p1);
            float ov = sigm(opre);
            float cn = fv * c[r] + iv * gv;
            c[r] = cn;
            float hv = ov * tanh_fast(cn);
            union { _Float16 f; unsigned short u; } cvh; cvh.f = (_Float16)hv;
            uint32 hu = cvh.u;
            uint32 part = (uint32)__builtin_amdgcn_ds_swizzle((int)hu, 0x041F);
            hdw[r] = (hu & 0xFFFFu) | (part << 16);
        }
        {
            _Float16* hwb = hbuf + (((t&1)*NGROUPS) + grp)*(16*HDIM);
            if (stl) {
                #pragma unroll
                for (int r = 0; r < 4; ++r) {
                    const int m = quad*4 + r;
                    uint32* dst = (uint32*)(hwb + m*HDIM + slc*8 + jj8);
                    __hip_atomic_store(dst, hdw[r], __ATOMIC_RELAXED, __HIP_MEMORY_SCOPE_AGENT);
                }
            }
            asm volatile("s_waitcnt vmcnt(0)" ::: "memory");
            if (L == 0) {
                int* myf = flags + (t&1)*(NGROUPS*NSLICES) + grp*NSLICES + slc;
                __hip_atomic_store(myf, t+1, __ATOMIC_RELAXED, __HIP_MEMORY_SCOPE_AGENT);
            }
        }
        #pragma unroll
        for (int kt = 0; kt < 4; ++kt) xcur[kt] = xnext[kt];
        tok_next = tok_nn;
    }

    if (slc == 0) {
        const int parF = (T_STEPS-1) & 1;
        int* fl = flags + parF*(NGROUPS*NSLICES) + grp*NSLICES + (L & 31);
        int cnt = 0;
        while (true) {
            int v = __hip_atomic_load(fl, __ATOMIC_RELAXED, __HIP_MEMORY_SCOPE_AGENT);
            if (__all(v >= T_STEPS)) break;
            if (++cnt > (1<<15)) break;
            __builtin_amdgcn_s_sleep(1);
        }
        asm volatile("" ::: "memory");
        const int m  = L >> 2;
        const int pp = L & 3;
        const _Float16* hr = hbuf + (parF*NGROUPS + grp)*(16*HDIM) + m*HDIM;
        const uint32* hp = (const uint32*)hr + pp*32;
        float sum = 0.f;
        #pragma unroll
        for (int d = 0; d < 32; ++d) {
            uint32 u = __hip_atomic_load(hp + d, __ATOMIC_RELAXED, __HIP_MEMORY_SCOPE_AGENT);
            union { uint32 u; _Float16 h[2]; } cv; cv.u = u;
            const int j = pp*64 + d*2;
            sum += (float)cv.h[0] * Wout[j] + (float)cv.h[1] * Wout[j+1];
        }
        sum += __int_as_float(__builtin_amdgcn_ds_swizzle(__float_as_int(sum), 0x041F));
        sum += __int_as_float(__builtin_amdgcn_ds_swizzle(__float_as_int(sum), 0x081F));
        if (pp == 0) out[grp*16 + m] = sigm(sum + bout[0]);
    }
}

// ============================================================================
extern "C" void kernel_launch(void* const* d_in, const int* in_sizes, int n_in,
                              void* d_out, int out_size, void* d_ws, size_t ws_size,
                              hipStream_t stream) {
    const int*   tokp = (const int*)  d_in[0];
    const float* emb  = (const float*)d_in[1];
    const float* Wih  = (const float*)d_in[2];
    const float* Whh  = (const float*)d_in[3];
    const float* bih  = (const float*)d_in[4];
    const float* bhh  = (const float*)d_in[5];
    const float* Wout = (const float*)d_in[6];
    const float* bout = (const float*)d_in[7];
    float* out = (float*)d_out;
    char*  ws  = (char*)d_ws;

    if (ws_size >= TABLE_BYTES) {
        // PATH B: table precompute (all-CU MFMA GEMM) + single-CU persistent LSTM
        _Float16* xgp = (_Float16*)ws;
        const int vtiles = (NVOCAB + 63) / 64;          // 782
        xg_table<<<vtiles*8, 64, 0, stream>>>(emb, Wih, bih, bhh, xgp);
        lstm_table<<<NGROUPS, 512, 0, stream>>>(tokp, Whh, Wout, bout, xgp, out);
    } else {
        // PATH A: round-1 proven fallback
        const int use16 = (ws_size >= (size_t)WS_NEED_BIG) ? 1 : 0;
        _Float16* emb16 = (_Float16*)(ws + EMB16_OFF);
        if (use16) {
            emb_cvt_kernel<<<1024, 256, 0, stream>>>(emb, emb16, NVOCAB*EDIM/4);
        }
        lstm_persist<<<NBLOCKS, 64, 0, stream>>>(tokp, emb, Wih, Whh, bih, bhh, Wout, bout,
                                                 out, ws, emb16, use16);
    }
}

// Round 3
// 4566.893 us; speedup vs baseline: 1.8455x; 1.1996x over previous
//
#include <hip/hip_runtime.h>

#define T_STEPS 2048
#define NBATCH  256
#define EDIM    128
#define HDIM    256
#define NVOCAB  50001
#define NGROUPS 16
#define NSLICES 32
#define NBLOCKS (NGROUPS*NSLICES)

typedef _Float16 half8 __attribute__((ext_vector_type(8)));
typedef float    floatx4 __attribute__((ext_vector_type(4)));
typedef int      intx8  __attribute__((ext_vector_type(8)));
typedef unsigned int uint32;

#define LOG2E      1.4426950408889634f
#define TWO_LOG2E  2.8853900817779268f

// pre-activations arrive pre-scaled by LOG2E (sigmoid) / 2*LOG2E (tanh)
__device__ __forceinline__ float sigE(float x){   // x = LOG2E * z ; returns sigmoid(z)
    return __builtin_amdgcn_rcpf(1.0f + __builtin_amdgcn_exp2f(-x));
}
__device__ __forceinline__ float tanhE(float x){  // x = 2*LOG2E * z ; returns tanh(z)
    return 2.0f * __builtin_amdgcn_rcpf(1.0f + __builtin_amdgcn_exp2f(-x)) - 1.0f;
}
__device__ __forceinline__ float sigm(float x){ return 1.0f/(1.0f + __expf(-x)); }
__device__ __forceinline__ float tanh_fast(float x){ return 2.0f/(1.0f + __expf(-2.0f*x)) - 1.0f; }

// ============================================================================
// PATH B (ws >= 102.4 MB): xg vocab table (pre-scaled) + single-CU persistent
// groups with MX-scaled K=128 fp8 recurrent MFMA.
// ============================================================================
#define TABLE_BYTES ((size_t)NVOCAB * 1024 * 2)   // 102,402,048

// xg_table: xgp[v][w][l15][n] (f16, 8 n contiguous = 16B) =
//   scale(gate) * ( sum_e W_ih[col,e]*emb[v,e] + b_ih[col] + b_hh[col] )
// col(n,w,l15) = (n>>1)*256 + w*32 + (n&1)*16 + l15 ; gate = n>>1 ; scale: g-gate 2*LOG2E else LOG2E
__global__ __launch_bounds__(64, 1) void xg_table(
    const float* __restrict__ emb,
    const float* __restrict__ Wih,
    const float* __restrict__ bih,
    const float* __restrict__ bhh,
    _Float16*    __restrict__ xgp)
{
    const int L  = threadIdx.x;
    const int l15 = L & 15;
    const int q   = L >> 4;
    const int w   = blockIdx.x & 7;
    const int v0  = (blockIdx.x >> 3) * 64;

    half8 bfr[8][4];
    float bias[8];
    #pragma unroll
    for (int n = 0; n < 8; ++n) {
        const int col = (n >> 1)*256 + w*32 + (n & 1)*16 + l15;
        bias[n] = bih[col] + bhh[col];
        #pragma unroll
        for (int kt = 0; kt < 4; ++kt) {
            const float* p = Wih + col*EDIM + kt*32 + q*8;
            const float4 f0 = *(const float4*)p;
            const float4 f1 = *(const float4*)(p + 4);
            half8 h;
            h[0]=(_Float16)f0.x; h[1]=(_Float16)f0.y; h[2]=(_Float16)f0.z; h[3]=(_Float16)f0.w;
            h[4]=(_Float16)f1.x; h[5]=(_Float16)f1.y; h[6]=(_Float16)f1.z; h[7]=(_Float16)f1.w;
            bfr[n][kt] = h;
        }
    }

    floatx4 acc[4][8];
    #pragma unroll
    for (int mt = 0; mt < 4; ++mt)
        #pragma unroll
        for (int n = 0; n < 8; ++n) acc[mt][n] = (floatx4){0.f,0.f,0.f,0.f};

    #pragma unroll
    for (int mt = 0; mt < 4; ++mt) {
        int v = v0 + mt*16 + l15;
        if (v > NVOCAB-1) v = NVOCAB-1;
        #pragma unroll
        for (int kt = 0; kt < 4; ++kt) {
            const float* p = emb + (size_t)v*EDIM + kt*32 + q*8;
            const float4 f0 = *(const float4*)p;
            const float4 f1 = *(const float4*)(p + 4);
            half8 a;
            a[0]=(_Float16)f0.x; a[1]=(_Float16)f0.y; a[2]=(_Float16)f0.z; a[3]=(_Float16)f0.w;
            a[4]=(_Float16)f1.x; a[5]=(_Float16)f1.y; a[6]=(_Float16)f1.z; a[7]=(_Float16)f1.w;
            #pragma unroll
            for (int n = 0; n < 8; ++n)
                acc[mt][n] = __builtin_amdgcn_mfma_f32_16x16x32_f16(a, bfr[n][kt], acc[mt][n], 0,0,0);
        }
    }

    #pragma unroll
    for (int mt = 0; mt < 4; ++mt) {
        #pragma unroll
        for (int r = 0; r < 4; ++r) {
            const int v = v0 + mt*16 + q*4 + r;
            if (v <= NVOCAB-1) {
                union { int4 i4; _Float16 h[8]; } pk;
                #pragma unroll
                for (int n = 0; n < 8; ++n) {
                    const float sc = ((n >> 1) == 2) ? TWO_LOG2E : LOG2E;
                    pk.h[n] = (_Float16)((acc[mt][n][r] + bias[n]) * sc);
                }
                *(int4*)(xgp + (size_t)v*1024 + w*128 + l15*8) = pk.i4;
            }
        }
    }
}

// Persistent LSTM: 16 blocks x 512 threads (8 waves, 1 CU/group).
// W_hh fp8-e4m3 register-resident, pre-scaled by LOG2E (2*LOG2E for g gate).
// Recurrent GEMM: mfma_scale_f32_16x16x128_f8f6f4 (K=128, unit scales) x2 kt x8 n.
// h broadcast via LDS fp8, one __syncthreads per step.
#define H8_STRIDE 272
#define H8_BUF    (16*H8_STRIDE)            // 4352 B per parity
#define SM_H8     0
#define SM_HF16   (2*H8_BUF)                // 8704
#define SM_RED    (SM_HF16 + 16*256*2)      // 16896
#define SM_TOTAL  (SM_RED + 256*4)          // 17920

__global__ __launch_bounds__(512, 2) void lstm_table(
    const int*   __restrict__ tok,
    const float* __restrict__ Whh,
    const float* __restrict__ Wout,
    const float* __restrict__ bout,
    const _Float16* __restrict__ xgp,
    float*       __restrict__ out)
{
    __shared__ char smem[SM_TOTAL];
    const int tid = threadIdx.x;
    const int w   = tid >> 6;
    const int L   = tid & 63;
    const int l15 = L & 15;
    const int q   = L >> 4;
    const int g16 = blockIdx.x * 16;

    // ---- W_hh -> fp8 MX fragments: wf[n][kt], 32 B/lane = k in [kt*128+q*32, +32) ----
    intx8 wf[8][2];
    #pragma unroll
    for (int n = 0; n < 8; ++n) {
        const int col = (n >> 1)*256 + w*32 + (n & 1)*16 + l15;
        const float sc = ((n >> 1) == 2) ? TWO_LOG2E : LOG2E;
        #pragma unroll
        for (int kt = 0; kt < 2; ++kt) {
            const float* p = Whh + col*HDIM + kt*128 + q*32;
            intx8 v;
            #pragma unroll
            for (int d = 0; d < 8; ++d) {
                const float4 f = *(const float4*)(p + d*4);
                int pk = __builtin_amdgcn_cvt_pk_fp8_f32(f.x*sc, f.y*sc, 0, false);
                pk     = __builtin_amdgcn_cvt_pk_fp8_f32(f.z*sc, f.w*sc, pk, true);
                v[d] = pk;
            }
            wf[n][kt] = v;
        }
    }

    // ---- pipeline init: xg(t=0) and tokens(t=1) ----
    union Hx { int4 v; _Float16 h[8]; };
    int4 xg_cur[4], xg_nxt[4];
    int4 tkc, tkn;
    {
        int4 tk0 = *(const int4*)(tok + g16 + q*4);
        const int* t0 = (const int*)&tk0;
        #pragma unroll
        for (int r = 0; r < 4; ++r)
            xg_cur[r] = *(const int4*)(xgp + (size_t)t0[r]*1024 + w*128 + l15*8);
        tkc = *(const int4*)(tok + NBATCH + g16 + q*4);
    }

    float c[8];
    #pragma unroll
    for (int i = 0; i < 8; ++i) c[i] = 0.f;

    #pragma unroll 1
    for (int t = 0; t < T_STEPS; ++t) {
        // prefetch tokens(t+2) and xg(t+1)
        if (t + 2 < T_STEPS) tkn = *(const int4*)(tok + (t+2)*NBATCH + g16 + q*4);
        if (t + 1 < T_STEPS) {
            const int* tc = (const int*)&tkc;
            #pragma unroll
            for (int r = 0; r < 4; ++r)
                xg_nxt[r] = *(const int4*)(xgp + (size_t)tc[r]*1024 + w*128 + l15*8);
        }

        // acc init from xg fragments (C/D layout: col=l15, row=q*4+r)
        floatx4 acc[8];
        #pragma unroll
        for (int r = 0; r < 4; ++r) {
            Hx hx; hx.v = xg_cur[r];
            #pragma unroll
            for (int n = 0; n < 8; ++n) acc[n][r] = (float)hx.h[n];
        }

        // recurrent GEMM: A = fp8 h from LDS, lane(m=l15,q) reads 32B at j=kt*128+q*32
        if (t > 0) {
            const char* hb = smem + SM_H8 + ((t-1) & 1)*H8_BUF + l15*H8_STRIDE + q*32;
            #pragma unroll
            for (int kt = 0; kt < 2; ++kt) {
                union { int4 v[2]; intx8 a; } af;
                af.v[0] = *(const int4*)(hb + kt*128);
                af.v[1] = *(const int4*)(hb + kt*128 + 16);
                #pragma unroll
                for (int n = 0; n < 8; ++n)
                    acc[n] = __builtin_amdgcn_mfma_scale_f32_16x16x128_f8f6f4(
                                 af.a, wf[n][kt], acc[n], 0, 0, 0, 127, 0, 127);
            }
        }

        // gates: lane holds i,f,g,o for (row=q*4+r, j=w*32+u*16+l15) at n={u,2+u,4+u,6+u}
        char* h8w = smem + SM_H8 + (t & 1)*H8_BUF;
        const bool last = (t == T_STEPS-1);
        #pragma unroll
        for (int u = 0; u < 2; ++u) {
            #pragma unroll
            for (int r = 0; r < 4; ++r) {
                const float iv = sigE(acc[0+u][r]);
                const float fv = sigE(acc[2+u][r]);
                const float gv = tanhE(acc[4+u][r]);
                const float ov = sigE(acc[6+u][r]);
                const int ci = u*4 + r;
                const float cn = fv * c[ci] + iv * gv;
                c[ci] = cn;
                const float hv = ov * tanhE(cn * TWO_LOG2E);
                const int row = q*4 + r;
                const int j   = w*32 + u*16 + l15;
                if (last) {
                    *(_Float16*)(smem + SM_HF16 + (row*256 + j)*2) = (_Float16)hv;
                } else {
                    const int pk = __builtin_amdgcn_cvt_pk_fp8_f32(hv, hv, 0, false);
                    *(char*)(h8w + row*H8_STRIDE + j) = (char)pk;
                }
            }
        }
        __syncthreads();

        #pragma unroll
        for (int r = 0; r < 4; ++r) xg_cur[r] = xg_nxt[r];
        tkc = tkn;
    }

    // ---- output: y = sigmoid(h_T . W_out + b) ----
    float* red = (float*)(smem + SM_RED);
    if (tid < 256) {
        const int b = tid >> 4, seg = tid & 15;
        const _Float16* hr = (const _Float16*)(smem + SM_HF16) + b*256 + seg*16;
        const float* wo = Wout + seg*16;
        float s = 0.f;
        #pragma unroll
        for (int jj = 0; jj < 16; ++jj) s += (float)hr[jj] * wo[jj];
        red[tid] = s;
    }
    __syncthreads();
    if (tid < 16) {
        float s = 0.f;
        #pragma unroll
        for (int k = 0; k < 16; ++k) s += red[tid*16 + k];
        out[g16 + tid] = sigm(s + bout[0]);
    }
}

// ============================================================================
// PATH A (fallback, ws < 102.4 MB): Round-1 kernel (proven, ~8.4 ms)
// ============================================================================
#define FLAGS_OFF   0
#define HBUF_OFF    4096
#define EMB16_OFF   (4096 + 262144)
#define EMB16_BYTES (NVOCAB*EDIM*2)
#define WS_NEED_BIG (EMB16_OFF + EMB16_BYTES)

__global__ void emb_cvt_kernel(const float* __restrict__ src, _Float16* __restrict__ dst, int n4){
    int stride = gridDim.x * blockDim.x;
    for (int i = blockIdx.x*blockDim.x + threadIdx.x; i < n4; i += stride) {
        const float4 v = ((const float4*)src)[i];
        union { _Float16 h[4]; uint2 u; } p;
        p.h[0] = (_Float16)v.x; p.h[1] = (_Float16)v.y;
        p.h[2] = (_Float16)v.z; p.h[3] = (_Float16)v.w;
        ((uint2*)dst)[i] = p.u;
    }
}

__global__ __launch_bounds__(64, 2) void lstm_persist(
    const int*   __restrict__ tok,
    const float* __restrict__ emb32,
    const float* __restrict__ Wih,
    const float* __restrict__ Whh,
    const float* __restrict__ bih,
    const float* __restrict__ bhh,
    const float* __restrict__ Wout,
    const float* __restrict__ bout,
    float*       __restrict__ out,
    char*        __restrict__ ws,
    const _Float16* __restrict__ emb16,
    int use16)
{
    const int L      = threadIdx.x;
    const int lane15 = L & 15;
    const int quad   = L >> 4;
    const int bid    = blockIdx.x;
    const int grp    = (bid & 7)*2 + (bid >> 8);
    const int slc    = (bid >> 3) & 31;

    int*      flags = (int*)(ws + FLAGS_OFF);
    _Float16* hbuf  = (_Float16*)(ws + HBUF_OFF);

    half8 bfr[2][12];
    float bias[2];
    #pragma unroll
    for (int tile = 0; tile < 2; ++tile) {
        const int nloc = tile*16 + lane15;
        const int gate = nloc >> 3;
        const int jj   = nloc & 7;
        const int ng   = gate*HDIM + slc*8 + jj;
        bias[tile] = bih[ng] + bhh[ng];
        #pragma unroll
        for (int kt = 0; kt < 12; ++kt) {
            const int k0 = kt*32 + quad*8;
            const float* p = (kt < 4) ? (Wih + ng*EDIM + k0)
                                      : (Whh + ng*HDIM + (k0 - EDIM));
            half8 h;
            #pragma unroll
            for (int i = 0; i < 8; ++i) h[i] = (_Float16)p[i];
            bfr[tile][kt] = h;
        }
    }

    const int btok = grp*16 + lane15;
    auto ldx = [&](int tk, int kt) -> half8 {
        const int k0 = kt*32 + quad*8;
        if (use16) {
            return *(const half8*)(emb16 + (long)tk*EDIM + k0);
        } else {
            const float* p = emb32 + (long)tk*EDIM + k0;
            half8 h;
            #pragma unroll
            for (int i = 0; i < 8; ++i) h[i] = (_Float16)p[i];
            return h;
        }
    };

    int tok_next = tok[NBATCH + btok];
    half8 xcur[4], xnext[4];
    {
        int tok0 = tok[btok];
        #pragma unroll
        for (int kt = 0; kt < 4; ++kt) xcur[kt] = ldx(tok0, kt);
    }

    float c[4] = {0.f, 0.f, 0.f, 0.f};
    const bool act = (lane15 < 8);
    const bool stl = act && !(lane15 & 1);
    const int  jj8 = lane15 & 7;

    #pragma unroll 1
    for (int t = 0; t < T_STEPS; ++t) {
        if (t + 1 < T_STEPS) {
            #pragma unroll
            for (int kt = 0; kt < 4; ++kt) xnext[kt] = ldx(tok_next, kt);
        }
        int tok_nn = 0;
        if (t + 2 < T_STEPS) tok_nn = tok[(t+2)*NBATCH + btok];

        floatx4 acc0 = {0.f,0.f,0.f,0.f};
        floatx4 acc1 = {0.f,0.f,0.f,0.f};

        #pragma unroll
        for (int kt = 0; kt < 4; ++kt) {
            acc0 = __builtin_amdgcn_mfma_f32_16x16x32_f16(xcur[kt], bfr[0][kt], acc0, 0,0,0);
            acc1 = __builtin_amdgcn_mfma_f32_16x16x32_f16(xcur[kt], bfr[1][kt], acc1, 0,0,0);
        }

        if (t > 0) {
            const int parR = (t-1) & 1;
            int* fl = flags + parR*(NGROUPS*NSLICES) + grp*NSLICES + (L & 31);
            int cnt = 0;
            while (true) {
                int v = __hip_atomic_load(fl, __ATOMIC_RELAXED, __HIP_MEMORY_SCOPE_AGENT);
                if (__all(v >= t)) break;
                if (++cnt > (1<<15)) break;
                __builtin_amdgcn_s_sleep(1);
            }
            asm volatile("" ::: "memory");
            const _Float16* hr = hbuf + (parR*NGROUPS + grp)*(16*HDIM) + lane15*HDIM;
            #pragma unroll
            for (int kt = 4; kt < 12; ++kt) {
                const int j0 = (kt-4)*32 + quad*8;
                const uint32* hp = (const uint32*)(hr + j0);
                union { uint32 u[4]; half8 h; } hf;
                hf.u[0] = __hip_atomic_load(hp+0, __ATOMIC_RELAXED, __HIP_MEMORY_SCOPE_AGENT);
                hf.u[1] = __hip_atomic_load(hp+1, __ATOMIC_RELAXED, __HIP_MEMORY_SCOPE_AGENT);
                hf.u[2] = __hip_atomic_load(hp+2, __ATOMIC_RELAXED, __HIP_MEMORY_SCOPE_AGENT);
                hf.u[3] = __hip_atomic_load(hp+3, __ATOMIC_RELAXED, __HIP_MEMORY_SCOPE_AGENT);
                acc0 = __builtin_amdgcn_mfma_f32_16x16x32_f16(hf.h, bfr[0][kt], acc0, 0,0,0);
                acc1 = __builtin_amdgcn_mfma_f32_16x16x32_f16(hf.h, bfr[1][kt], acc1, 0,0,0);
            }
        }

        uint32 hdw[4];
        #pragma unroll
        for (int r = 0; r < 4; ++r) {
            float p0 = acc0[r] + bias[0];
            float p1 = acc1[r] + bias[1];
            float fpre = __int_as_float(__builtin_amdgcn_ds_swizzle(__float_as_int(p0), 0x201F));
            float opre = __int_as_float(__builtin_amdgcn_ds_swizzle(__float_as_int(p1), 0x201F));
            float iv = sigm(p0);
            float fv = sigm(fpre);
            float gv = tanh_fast(p1);
            float ov = sigm(opre);
            float cn = fv * c[r] + iv * gv;
            c[r] = cn;
            float hv = ov * tanh_fast(cn);
            union { _Float16 f; unsigned short u; } cvh; cvh.f = (_Float16)hv;
            uint32 hu = cvh.u;
            uint32 part = (uint32)__builtin_amdgcn_ds_swizzle((int)hu, 0x041F);
            hdw[r] = (hu & 0xFFFFu) | (part << 16);
        }
        {
            _Float16* hwb = hbuf + (((t&1)*NGROUPS) + grp)*(16*HDIM);
            if (stl) {
                #pragma unroll
                for (int r = 0; r < 4; ++r) {
                    const int m = quad*4 + r;
                    uint32* dst = (uint32*)(hwb + m*HDIM + slc*8 + jj8);
                    __hip_atomic_store(dst, hdw[r], __ATOMIC_RELAXED, __HIP_MEMORY_SCOPE_AGENT);
                }
            }
            asm volatile("s_waitcnt vmcnt(0)" ::: "memory");
            if (L == 0) {
                int* myf = flags + (t&1)*(NGROUPS*NSLICES) + grp*NSLICES + slc;
                __hip_atomic_store(myf, t+1, __ATOMIC_RELAXED, __HIP_MEMORY_SCOPE_AGENT);
            }
        }
        #pragma unroll
        for (int kt = 0; kt < 4; ++kt) xcur[kt] = xnext[kt];
        tok_next = tok_nn;
    }

    if (slc == 0) {
        const int parF = (T_STEPS-1) & 1;
        int* fl = flags + parF*(NGROUPS*NSLICES) + grp*NSLICES + (L & 31);
        int cnt = 0;
        while (true) {
            int v = __hip_atomic_load(fl, __ATOMIC_RELAXED, __HIP_MEMORY_SCOPE_AGENT);
            if (__all(v >= T_STEPS)) break;
            if (++cnt > (1<<15)) break;
            __builtin_amdgcn_s_sleep(1);
        }
        asm volatile("" ::: "memory");
        const int m  = L >> 2;
        const int pp = L & 3;
        const _Float16* hr = hbuf + (parF*NGROUPS + grp)*(16*HDIM) + m*HDIM;
        const uint32* hp = (const uint32*)hr + pp*32;
        float sum = 0.f;
        #pragma unroll
        for (int d = 0; d < 32; ++d) {
            uint32 u = __hip_atomic_load(hp + d, __ATOMIC_RELAXED, __HIP_MEMORY_SCOPE_AGENT);
            union { uint32 u; _Float16 h[2]; } cv; cv.u = u;
            const int j = pp*64 + d*2;
            sum += (float)cv.h[0] * Wout[j] + (float)cv.h[1] * Wout[j+1];
        }
        sum += __int_as_float(__builtin_amdgcn_ds_swizzle(__float_as_int(sum), 0x041F));
        sum += __int_as_float(__builtin_amdgcn_ds_swizzle(__float_as_int(sum), 0x081F));
        if (pp == 0) out[grp*16 + m] = sigm(sum + bout[0]);
    }
}

// ============================================================================
extern "C" void kernel_launch(void* const* d_in, const int* in_sizes, int n_in,
                              void* d_out, int out_size, void* d_ws, size_t ws_size,
                              hipStream_t stream) {
    const int*   tokp = (const int*)  d_in[0];
    const float* emb  = (const float*)d_in[1];
    const float* Wih  = (const float*)d_in[2];
    const float* Whh  = (const float*)d_in[3];
    const float* bih  = (const float*)d_in[4];
    const float* bhh  = (const float*)d_in[5];
    const float* Wout = (const float*)d_in[6];
    const float* bout = (const float*)d_in[7];
    float* out = (float*)d_out;
    char*  ws  = (char*)d_ws;

    if (ws_size >= TABLE_BYTES) {
        _Float16* xgp = (_Float16*)ws;
        const int vtiles = (NVOCAB + 63) / 64;          // 782
        xg_table<<<vtiles*8, 64, 0, stream>>>(emb, Wih, bih, bhh, xgp);
        lstm_table<<<NGROUPS, 512, 0, stream>>>(tokp, Whh, Wout, bout, xgp, out);
    } else {
        const int use16 = (ws_size >= (size_t)WS_NEED_BIG) ? 1 : 0;
        _Float16* emb16 = (_Float16*)(ws + EMB16_OFF);
        if (use16) {
            emb_cvt_kernel<<<1024, 256, 0, stream>>>(emb, emb16, NVOCAB*EDIM/4);
        }
        lstm_persist<<<NBLOCKS, 64, 0, stream>>>(tokp, emb, Wih, Whh, bih, bhh, Wout, bout,
                                                 out, ws, emb16, use16);
    }
}

// Round 4
// 4039.872 us; speedup vs baseline: 2.0863x; 1.1305x over previous
//
#include <hip/hip_runtime.h>

#define T_STEPS 2048
#define NBATCH  256
#define EDIM    128
#define HDIM    256
#define NVOCAB  50001
#define NGROUPS 16
#define NSLICES 32
#define NBLOCKS (NGROUPS*NSLICES)

typedef _Float16 half8 __attribute__((ext_vector_type(8)));
typedef float    floatx4 __attribute__((ext_vector_type(4)));
typedef int      intx8  __attribute__((ext_vector_type(8)));
typedef unsigned int uint32;

#define LOG2E      1.4426950408889634f
#define TWO_LOG2E  2.8853900817779268f

// pre-activations arrive pre-scaled by LOG2E (sigmoid) / 2*LOG2E (tanh)
__device__ __forceinline__ float sigE(float x){   // x = LOG2E * z ; returns sigmoid(z)
    return __builtin_amdgcn_rcpf(1.0f + __builtin_amdgcn_exp2f(-x));
}
__device__ __forceinline__ float tanhE(float x){  // x = 2*LOG2E * z ; returns tanh(z)
    return 2.0f * __builtin_amdgcn_rcpf(1.0f + __builtin_amdgcn_exp2f(-x)) - 1.0f;
}
__device__ __forceinline__ float sigm(float x){ return 1.0f/(1.0f + __expf(-x)); }
__device__ __forceinline__ float tanh_fast(float x){ return 2.0f/(1.0f + __expf(-2.0f*x)) - 1.0f; }

// ============================================================================
// PATH B (ws >= 102.4 MB): xg vocab table (pre-scaled) + 32-CU persistent LSTM
// (8 batch rows per CU), MX-scaled K=128 fp8 recurrent MFMA, shuffle-balanced
// gate math.
// ============================================================================
#define TABLE_BYTES ((size_t)NVOCAB * 1024 * 2)   // 102,402,048

// xg_table: xgp[v][w][l15][n] (f16, 8 n contiguous = 16B) =
//   scale(gate) * ( sum_e W_ih[col,e]*emb[v,e] + b_ih[col] + b_hh[col] )
// col(n,w,l15) = (n>>1)*256 + w*32 + (n&1)*16 + l15 ; gate = n>>1 ; g-gate scale 2*LOG2E else LOG2E
__global__ __launch_bounds__(64, 1) void xg_table(
    const float* __restrict__ emb,
    const float* __restrict__ Wih,
    const float* __restrict__ bih,
    const float* __restrict__ bhh,
    _Float16*    __restrict__ xgp)
{
    const int L  = threadIdx.x;
    const int l15 = L & 15;
    const int q   = L >> 4;
    const int w   = blockIdx.x & 7;
    const int v0  = (blockIdx.x >> 3) * 64;

    half8 bfr[8][4];
    float bias[8];
    #pragma unroll
    for (int n = 0; n < 8; ++n) {
        const int col = (n >> 1)*256 + w*32 + (n & 1)*16 + l15;
        bias[n] = bih[col] + bhh[col];
        #pragma unroll
        for (int kt = 0; kt < 4; ++kt) {
            const float* p = Wih + col*EDIM + kt*32 + q*8;
            const float4 f0 = *(const float4*)p;
            const float4 f1 = *(const float4*)(p + 4);
            half8 h;
            h[0]=(_Float16)f0.x; h[1]=(_Float16)f0.y; h[2]=(_Float16)f0.z; h[3]=(_Float16)f0.w;
            h[4]=(_Float16)f1.x; h[5]=(_Float16)f1.y; h[6]=(_Float16)f1.z; h[7]=(_Float16)f1.w;
            bfr[n][kt] = h;
        }
    }

    floatx4 acc[4][8];
    #pragma unroll
    for (int mt = 0; mt < 4; ++mt)
        #pragma unroll
        for (int n = 0; n < 8; ++n) acc[mt][n] = (floatx4){0.f,0.f,0.f,0.f};

    #pragma unroll
    for (int mt = 0; mt < 4; ++mt) {
        int v = v0 + mt*16 + l15;
        if (v > NVOCAB-1) v = NVOCAB-1;
        #pragma unroll
        for (int kt = 0; kt < 4; ++kt) {
            const float* p = emb + (size_t)v*EDIM + kt*32 + q*8;
            const float4 f0 = *(const float4*)p;
            const float4 f1 = *(const float4*)(p + 4);
            half8 a;
            a[0]=(_Float16)f0.x; a[1]=(_Float16)f0.y; a[2]=(_Float16)f0.z; a[3]=(_Float16)f0.w;
            a[4]=(_Float16)f1.x; a[5]=(_Float16)f1.y; a[6]=(_Float16)f1.z; a[7]=(_Float16)f1.w;
            #pragma unroll
            for (int n = 0; n < 8; ++n)
                acc[mt][n] = __builtin_amdgcn_mfma_f32_16x16x32_f16(a, bfr[n][kt], acc[mt][n], 0,0,0);
        }
    }

    #pragma unroll
    for (int mt = 0; mt < 4; ++mt) {
        #pragma unroll
        for (int r = 0; r < 4; ++r) {
            const int v = v0 + mt*16 + q*4 + r;
            if (v <= NVOCAB-1) {
                union { int4 i4; _Float16 h[8]; } pk;
                #pragma unroll
                for (int n = 0; n < 8; ++n) {
                    const float sc = ((n >> 1) == 2) ? TWO_LOG2E : LOG2E;
                    pk.h[n] = (_Float16)((acc[mt][n][r] + bias[n]) * sc);
                }
                *(int4*)(xgp + (size_t)v*1024 + w*128 + l15*8) = pk.i4;
            }
        }
    }
}

// Persistent LSTM: 32 blocks x 512 threads, 8 batch rows per block.
// Tile rows 8..15 are dead (A aliased to rows 0..7); gate math rebalanced to
// all 64 lanes via one shfl_xor(32) round: lanes q<2 keep even-n (u=0 cols),
// lanes q>=2 receive odd-n (u=1 cols). Cell at lane(l15,q): row=(q&1)*4+r,
// j = w*32 + (q>>1)*16 + l15.
#define NBLK2     32
#define H8_STRIDE 272
#define H8_BUF    (8*H8_STRIDE)            // 2176 B per parity
#define SM_H8     0
#define SM_HF16   (2*H8_BUF)               // 4352
#define SM_RED    (SM_HF16 + 8*256*2)      // 8448
#define SM_TOTAL  (SM_RED + 128*4)         // 8960

__global__ __launch_bounds__(512, 2) void lstm_table(
    const int*   __restrict__ tok,
    const float* __restrict__ Whh,
    const float* __restrict__ Wout,
    const float* __restrict__ bout,
    const _Float16* __restrict__ xgp,
    float*       __restrict__ out)
{
    __shared__ char smem[SM_TOTAL];
    const int tid = threadIdx.x;
    const int w   = tid >> 6;
    const int L   = tid & 63;
    const int l15 = L & 15;
    const int q   = L >> 4;
    const int g8  = blockIdx.x * 8;
    const bool lo = (q < 2);

    // ---- W_hh -> fp8 MX fragments: wf[n][kt], 32 B/lane = k in [kt*128+q*32, +32) ----
    intx8 wf[8][2];
    #pragma unroll
    for (int n = 0; n < 8; ++n) {
        const int col = (n >> 1)*256 + w*32 + (n & 1)*16 + l15;
        const float sc = ((n >> 1) == 2) ? TWO_LOG2E : LOG2E;
        #pragma unroll
        for (int kt = 0; kt < 2; ++kt) {
            const float* p = Whh + col*HDIM + kt*128 + q*32;
            intx8 v;
            #pragma unroll
            for (int d = 0; d < 8; ++d) {
                const float4 f = *(const float4*)(p + d*4);
                int pk = __builtin_amdgcn_cvt_pk_fp8_f32(f.x*sc, f.y*sc, 0, false);
                pk     = __builtin_amdgcn_cvt_pk_fp8_f32(f.z*sc, f.w*sc, pk, true);
                v[d] = pk;
            }
            wf[n][kt] = v;
        }
    }

    // ---- pipeline init: xg(t=0) and tokens(t=1) (only q<2 lanes carry xg) ----
    union Hx { int4 v; _Float16 h[8]; };
    int4 xg_cur[4], xg_nxt[4];
    int4 tkc, tkn;
    if (lo) {
        int4 tk0 = *(const int4*)(tok + g8 + q*4);
        const int* t0 = (const int*)&tk0;
        #pragma unroll
        for (int r = 0; r < 4; ++r)
            xg_cur[r] = *(const int4*)(xgp + (size_t)t0[r]*1024 + w*128 + l15*8);
        tkc = *(const int4*)(tok + NBATCH + g8 + q*4);
    }

    float c[4] = {0.f, 0.f, 0.f, 0.f};

    #pragma unroll 1
    for (int t = 0; t < T_STEPS; ++t) {
        // prefetch tokens(t+2) and xg(t+1)  (q<2 lanes only — halves traffic)
        if (lo) {
            if (t + 2 < T_STEPS) tkn = *(const int4*)(tok + (t+2)*NBATCH + g8 + q*4);
            if (t + 1 < T_STEPS) {
                const int* tc = (const int*)&tkc;
                #pragma unroll
                for (int r = 0; r < 4; ++r)
                    xg_nxt[r] = *(const int4*)(xgp + (size_t)tc[r]*1024 + w*128 + l15*8);
            }
        }

        // acc init: q<2 lanes from xg fragments (C/D: col=l15, row=q*4+r); others 0
        floatx4 acc[8];
        #pragma unroll
        for (int n = 0; n < 8; ++n) acc[n] = (floatx4){0.f,0.f,0.f,0.f};
        if (lo) {
            #pragma unroll
            for (int r = 0; r < 4; ++r) {
                Hx hx; hx.v = xg_cur[r];
                #pragma unroll
                for (int n = 0; n < 8; ++n) acc[n][r] = (float)hx.h[n];
            }
        }

        // recurrent GEMM: A = fp8 h from LDS (rows aliased l15&7), 32B/lane
        if (t > 0) {
            const char* hb = smem + SM_H8 + ((t-1) & 1)*H8_BUF + (l15 & 7)*H8_STRIDE + q*32;
            #pragma unroll
            for (int kt = 0; kt < 2; ++kt) {
                union { int4 v[2]; intx8 a; } af;
                af.v[0] = *(const int4*)(hb + kt*128);
                af.v[1] = *(const int4*)(hb + kt*128 + 16);
                #pragma unroll
                for (int n = 0; n < 8; ++n)
                    acc[n] = __builtin_amdgcn_mfma_scale_f32_16x16x128_f8f6f4(
                                 af.a, wf[n][kt], acc[n], 0, 0, 0, 127, 0, 127);
            }
        }

        // rebalance: odd-n (u=1) accumulators cross to lanes q>=2 via lane^32
        float P[4][4];   // [gate][r] pre-activations for this lane's 4 cells
        #pragma unroll
        for (int g = 0; g < 4; ++g) {
            #pragma unroll
            for (int r = 0; r < 4; ++r) {
                const float xch = __shfl_xor(acc[2*g+1][r], 32, 64);
                P[g][r] = lo ? acc[2*g][r] : xch;
            }
        }

        // gates: cell (row=(q&1)*4+r, j=w*32+(q>>1)*16+l15)
        char* h8w = smem + SM_H8 + (t & 1)*H8_BUF;
        const int rowb = (q & 1)*4;
        const int j    = w*32 + (q >> 1)*16 + l15;
        const bool last = (t == T_STEPS-1);
        #pragma unroll
        for (int r = 0; r < 4; ++r) {
            const float iv = sigE(P[0][r]);
            const float fv = sigE(P[1][r]);
            const float gv = tanhE(P[2][r]);
            const float ov = sigE(P[3][r]);
            const float cn = fv * c[r] + iv * gv;
            c[r] = cn;
            const float hv = ov * tanhE(cn * TWO_LOG2E);
            const int row = rowb + r;
            if (last) {
                *(_Float16*)(smem + SM_HF16 + (row*256 + j)*2) = (_Float16)hv;
            } else {
                const int pk = __builtin_amdgcn_cvt_pk_fp8_f32(hv, hv, 0, false);
                *(char*)(h8w + row*H8_STRIDE + j) = (char)pk;
            }
        }
        __syncthreads();

        if (lo) {
            #pragma unroll
            for (int r = 0; r < 4; ++r) xg_cur[r] = xg_nxt[r];
            tkc = tkn;
        }
    }

    // ---- output: y = sigmoid(h_T . W_out + b) for 8 rows ----
    float* red = (float*)(smem + SM_RED);
    if (tid < 128) {
        const int b = tid >> 4, seg = tid & 15;
        const _Float16* hr = (const _Float16*)(smem + SM_HF16) + b*256 + seg*16;
        const float* wo = Wout + seg*16;
        float s = 0.f;
        #pragma unroll
        for (int jj = 0; jj < 16; ++jj) s += (float)hr[jj] * wo[jj];
        red[tid] = s;
    }
    __syncthreads();
    if (tid < 8) {
        float s = 0.f;
        #pragma unroll
        for (int k = 0; k < 16; ++k) s += red[tid*16 + k];
        out[g8 + tid] = sigm(s + bout[0]);
    }
}

// ============================================================================
// PATH A (fallback, ws < 102.4 MB): Round-1 kernel (proven, ~8.4 ms)
// ============================================================================
#define FLAGS_OFF   0
#define HBUF_OFF    4096
#define EMB16_OFF   (4096 + 262144)
#define EMB16_BYTES (NVOCAB*EDIM*2)
#define WS_NEED_BIG (EMB16_OFF + EMB16_BYTES)

__global__ void emb_cvt_kernel(const float* __restrict__ src, _Float16* __restrict__ dst, int n4){
    int stride = gridDim.x * blockDim.x;
    for (int i = blockIdx.x*blockDim.x + threadIdx.x; i < n4; i += stride) {
        const float4 v = ((const float4*)src)[i];
        union { _Float16 h[4]; uint2 u; } p;
        p.h[0] = (_Float16)v.x; p.h[1] = (_Float16)v.y;
        p.h[2] = (_Float16)v.z; p.h[3] = (_Float16)v.w;
        ((uint2*)dst)[i] = p.u;
    }
}

__global__ __launch_bounds__(64, 2) void lstm_persist(
    const int*   __restrict__ tok,
    const float* __restrict__ emb32,
    const float* __restrict__ Wih,
    const float* __restrict__ Whh,
    const float* __restrict__ bih,
    const float* __restrict__ bhh,
    const float* __restrict__ Wout,
    const float* __restrict__ bout,
    float*       __restrict__ out,
    char*        __restrict__ ws,
    const _Float16* __restrict__ emb16,
    int use16)
{
    const int L      = threadIdx.x;
    const int lane15 = L & 15;
    const int quad   = L >> 4;
    const int bid    = blockIdx.x;
    const int grp    = (bid & 7)*2 + (bid >> 8);
    const int slc    = (bid >> 3) & 31;

    int*      flags = (int*)(ws + FLAGS_OFF);
    _Float16* hbuf  = (_Float16*)(ws + HBUF_OFF);

    half8 bfr[2][12];
    float bias[2];
    #pragma unroll
    for (int tile = 0; tile < 2; ++tile) {
        const int nloc = tile*16 + lane15;
        const int gate = nloc >> 3;
        const int jj   = nloc & 7;
        const int ng   = gate*HDIM + slc*8 + jj;
        bias[tile] = bih[ng] + bhh[ng];
        #pragma unroll
        for (int kt = 0; kt < 12; ++kt) {
            const int k0 = kt*32 + quad*8;
            const float* p = (kt < 4) ? (Wih + ng*EDIM + k0)
                                      : (Whh + ng*HDIM + (k0 - EDIM));
            half8 h;
            #pragma unroll
            for (int i = 0; i < 8; ++i) h[i] = (_Float16)p[i];
            bfr[tile][kt] = h;
        }
    }

    const int btok = grp*16 + lane15;
    auto ldx = [&](int tk, int kt) -> half8 {
        const int k0 = kt*32 + quad*8;
        if (use16) {
            return *(const half8*)(emb16 + (long)tk*EDIM + k0);
        } else {
            const float* p = emb32 + (long)tk*EDIM + k0;
            half8 h;
            #pragma unroll
            for (int i = 0; i < 8; ++i) h[i] = (_Float16)p[i];
            return h;
        }
    };

    int tok_next = tok[NBATCH + btok];
    half8 xcur[4], xnext[4];
    {
        int tok0 = tok[btok];
        #pragma unroll
        for (int kt = 0; kt < 4; ++kt) xcur[kt] = ldx(tok0, kt);
    }

    float c[4] = {0.f, 0.f, 0.f, 0.f};
    const bool act = (lane15 < 8);
    const bool stl = act && !(lane15 & 1);
    const int  jj8 = lane15 & 7;

    #pragma unroll 1
    for (int t = 0; t < T_STEPS; ++t) {
        if (t + 1 < T_STEPS) {
            #pragma unroll
            for (int kt = 0; kt < 4; ++kt) xnext[kt] = ldx(tok_next, kt);
        }
        int tok_nn = 0;
        if (t + 2 < T_STEPS) tok_nn = tok[(t+2)*NBATCH + btok];

        floatx4 acc0 = {0.f,0.f,0.f,0.f};
        floatx4 acc1 = {0.f,0.f,0.f,0.f};

        #pragma unroll
        for (int kt = 0; kt < 4; ++kt) {
            acc0 = __builtin_amdgcn_mfma_f32_16x16x32_f16(xcur[kt], bfr[0][kt], acc0, 0,0,0);
            acc1 = __builtin_amdgcn_mfma_f32_16x16x32_f16(xcur[kt], bfr[1][kt], acc1, 0,0,0);
        }

        if (t > 0) {
            const int parR = (t-1) & 1;
            int* fl = flags + parR*(NGROUPS*NSLICES) + grp*NSLICES + (L & 31);
            int cnt = 0;
            while (true) {
                int v = __hip_atomic_load(fl, __ATOMIC_RELAXED, __HIP_MEMORY_SCOPE_AGENT);
                if (__all(v >= t)) break;
                if (++cnt > (1<<15)) break;
                __builtin_amdgcn_s_sleep(1);
            }
            asm volatile("" ::: "memory");
            const _Float16* hr = hbuf + (parR*NGROUPS + grp)*(16*HDIM) + lane15*HDIM;
            #pragma unroll
            for (int kt = 4; kt < 12; ++kt) {
                const int j0 = (kt-4)*32 + quad*8;
                const uint32* hp = (const uint32*)(hr + j0);
                union { uint32 u[4]; half8 h; } hf;
                hf.u[0] = __hip_atomic_load(hp+0, __ATOMIC_RELAXED, __HIP_MEMORY_SCOPE_AGENT);
                hf.u[1] = __hip_atomic_load(hp+1, __ATOMIC_RELAXED, __HIP_MEMORY_SCOPE_AGENT);
                hf.u[2] = __hip_atomic_load(hp+2, __ATOMIC_RELAXED, __HIP_MEMORY_SCOPE_AGENT);
                hf.u[3] = __hip_atomic_load(hp+3, __ATOMIC_RELAXED, __HIP_MEMORY_SCOPE_AGENT);
                acc0 = __builtin_amdgcn_mfma_f32_16x16x32_f16(hf.h, bfr[0][kt], acc0, 0,0,0);
                acc1 = __builtin_amdgcn_mfma_f32_16x16x32_f16(hf.h, bfr[1][kt], acc1, 0,0,0);
            }
        }

        uint32 hdw[4];
        #pragma unroll
        for (int r = 0; r < 4; ++r) {
            float p0 = acc0[r] + bias[0];
            float p1 = acc1[r] + bias[1];
            float fpre = __int_as_float(__builtin_amdgcn_ds_swizzle(__float_as_int(p0), 0x201F));
            float opre = __int_as_float(__builtin_amdgcn_ds_swizzle(__float_as_int(p1), 0x201F));
            float iv = sigm(p0);
            float fv = sigm(fpre);
            float gv = tanh_fast(p1);
            float ov = sigm(opre);
            float cn = fv * c[r] + iv * gv;
            c[r] = cn;
            float hv = ov * tanh_fast(cn);
            union { _Float16 f; unsigned short u; } cvh; cvh.f = (_Float16)hv;
            uint32 hu = cvh.u;
            uint32 part = (uint32)__builtin_amdgcn_ds_swizzle((int)hu, 0x041F);
            hdw[r] = (hu & 0xFFFFu) | (part << 16);
        }
        {
            _Float16* hwb = hbuf + (((t&1)*NGROUPS) + grp)*(16*HDIM);
            if (stl) {
                #pragma unroll
                for (int r = 0; r < 4; ++r) {
                    const int m = quad*4 + r;
                    uint32* dst = (uint32*)(hwb + m*HDIM + slc*8 + jj8);
                    __hip_atomic_store(dst, hdw[r], __ATOMIC_RELAXED, __HIP_MEMORY_SCOPE_AGENT);
                }
            }
            asm volatile("s_waitcnt vmcnt(0)" ::: "memory");
            if (L == 0) {
                int* myf = flags + (t&1)*(NGROUPS*NSLICES) + grp*NSLICES + slc;
                __hip_atomic_store(myf, t+1, __ATOMIC_RELAXED, __HIP_MEMORY_SCOPE_AGENT);
            }
        }
        #pragma unroll
        for (int kt = 0; kt < 4; ++kt) xcur[kt] = xnext[kt];
        tok_next = tok_nn;
    }

    if (slc == 0) {
        const int parF = (T_STEPS-1) & 1;
        int* fl = flags + parF*(NGROUPS*NSLICES) + grp*NSLICES + (L & 31);
        int cnt = 0;
        while (true) {
            int v = __hip_atomic_load(fl, __ATOMIC_RELAXED, __HIP_MEMORY_SCOPE_AGENT);
            if (__all(v >= T_STEPS)) break;
            if (++cnt > (1<<15)) break;
            __builtin_amdgcn_s_sleep(1);
        }
        asm volatile("" ::: "memory");
        const int m  = L >> 2;
        const int pp = L & 3;
        const _Float16* hr = hbuf + (parF*NGROUPS + grp)*(16*HDIM) + m*HDIM;
        const uint32* hp = (const uint32*)hr + pp*32;
        float sum = 0.f;
        #pragma unroll
        for (int d = 0; d < 32; ++d) {
            uint32 u = __hip_atomic_load(hp + d, __ATOMIC_RELAXED, __HIP_MEMORY_SCOPE_AGENT);
            union { uint32 u; _Float16 h[2]; } cv; cv.u = u;
            const int j = pp*64 + d*2;
            sum += (float)cv.h[0] * Wout[j] + (float)cv.h[1] * Wout[j+1];
        }
        sum += __int_as_float(__builtin_amdgcn_ds_swizzle(__float_as_int(sum), 0x041F));
        sum += __int_as_float(__builtin_amdgcn_ds_swizzle(__float_as_int(sum), 0x081F));
        if (pp == 0) out[grp*16 + m] = sigm(sum + bout[0]);
    }
}

// ============================================================================
extern "C" void kernel_launch(void* const* d_in, const int* in_sizes, int n_in,
                              void* d_out, int out_size, void* d_ws, size_t ws_size,
                              hipStream_t stream) {
    const int*   tokp = (const int*)  d_in[0];
    const float* emb  = (const float*)d_in[1];
    const float* Wih  = (const float*)d_in[2];
    const float* Whh  = (const float*)d_in[3];
    const float* bih  = (const float*)d_in[4];
    const float* bhh  = (const float*)d_in[5];
    const float* Wout = (const float*)d_in[6];
    const float* bout = (const float*)d_in[7];
    float* out = (float*)d_out;
    char*  ws  = (char*)d_ws;

    if (ws_size >= TABLE_BYTES) {
        _Float16* xgp = (_Float16*)ws;
        const int vtiles = (NVOCAB + 63) / 64;          // 782
        xg_table<<<vtiles*8, 64, 0, stream>>>(emb, Wih, bih, bhh, xgp);
        lstm_table<<<NBLK2, 512, 0, stream>>>(tokp, Whh, Wout, bout, xgp, out);
    } else {
        const int use16 = (ws_size >= (size_t)WS_NEED_BIG) ? 1 : 0;
        _Float16* emb16 = (_Float16*)(ws + EMB16_OFF);
        if (use16) {
            emb_cvt_kernel<<<1024, 256, 0, stream>>>(emb, emb16, NVOCAB*EDIM/4);
        }
        lstm_persist<<<NBLOCKS, 64, 0, stream>>>(tokp, emb, Wih, Whh, bih, bhh, Wout, bout,
                                                 out, ws, emb16, use16);
    }
}